// Round 28
// baseline (2567.244 us; speedup 1.0000x reference)
//
#include <hip/hip_runtime.h>

typedef unsigned long long u64;
typedef unsigned int u32;

#define Bn 8
#define Nn 8192
#define Sn 2048
#define Kn 32
#define CIN 35
#define COUT 128

// ---------------------------------------------------------------------------
// Kernel 1: fold the 3 bias-only linear layers into one: Wc[35][128], bc[128]
// ---------------------------------------------------------------------------
__global__ __launch_bounds__(128) void fold_kernel(
    const float* __restrict__ w0, const float* __restrict__ b0,
    const float* __restrict__ w1, const float* __restrict__ b1,
    const float* __restrict__ w2, const float* __restrict__ b2,
    float* __restrict__ Wc, float* __restrict__ bc)
{
    __shared__ float W01[35][64];
    __shared__ float bb[64];
    const int t = threadIdx.x;
    for (int o = t; o < 35 * 64; o += 128) {
        int i = o >> 6, j = o & 63;
        float acc = 0.0f;
        for (int c = 0; c < 64; ++c) acc = fmaf(w0[i * 64 + c], w1[c * 64 + j], acc);
        W01[i][j] = acc;
    }
    for (int j = t; j < 64; j += 128) {
        float acc = b1[j];
        for (int c = 0; c < 64; ++c) acc = fmaf(b0[c], w1[c * 64 + j], acc);
        bb[j] = acc;
    }
    __syncthreads();
    for (int o = t; o < 35 * 128; o += 128) {
        int i = o >> 7, j = o & 127;
        float acc = 0.0f;
        for (int c = 0; c < 64; ++c) acc = fmaf(W01[i][c], w2[c * 128 + j], acc);
        Wc[o] = acc;
    }
    for (int j = t; j < 128; j += 128) {
        float acc = b2[j];
        for (int c = 0; c < 64; ++c) acc = fmaf(bb[c], w2[c * 128 + j], acc);
        bc[j] = acc;
    }
}

// ---------------------------------------------------------------------------
// Kernel 2: FPS — ARITHMETIC FROZEN (bit-exact vs mirror, R23-verified):
//   d = fma(dz,dz, fma(dx,dx, dy*dy)), f32 dist state, strict >, first-idx ties
// R28 perf change: coords live ONLY in LDS (read per-iteration via
// conflict-free ds_read on the LDS pipe, overlapping VALU) — registers hold
// just the 16 dist floats. R24-27 showed the allocator parks big coord
// arrays in AGPRs (accvgpr VALU tax); this removes them from registers
// entirely. Ownership re-strided: thread t owns j = p*512+t, so LDS reads
// are lane-consecutive (0 bank conflicts; also fixes R27's 190k conflicts).
// 512 thr (2 waves/SIMD for latency hiding), 1 barrier/iter, winner via
// LDS broadcast, packed-key first-index ties on the true index j.
// ---------------------------------------------------------------------------
#define REP16(M) M(0) M(1) M(2) M(3) M(4) M(5) M(6) M(7) \
                 M(8) M(9) M(10) M(11) M(12) M(13) M(14) M(15)

__global__ __launch_bounds__(512, 1) void fps_kernel(
    const float* __restrict__ xyz, float* __restrict__ new_xyz)
{
    extern __shared__ float lds[];
    float* xs = lds;            // [8192]
    float* ys = lds + Nn;       // [8192]
    float* zs = lds + 2 * Nn;   // [8192]
    __shared__ u64 part[2][8];

    const int b = blockIdx.x;
    const int t = threadIdx.x;
    const int lane = t & 63;
    const int wid = t >> 6;  // 8 waves
    const float* base = xyz + (size_t)b * (Nn * 3);

    // dist state: 16 named scalars (fits arch VGPRs easily)
#define FPS_DECL(i) float dist##i = 1e10f;
    REP16(FPS_DECL)
#undef FPS_DECL

    // stage coords into LDS (linear SoA; winner lookup stays xs[widx])
    for (int p = 0; p < 16; ++p) {
        int j = p * 512 + t;
        xs[j] = base[j * 3 + 0];
        ys[j] = base[j * 3 + 1];
        zs[j] = base[j * 3 + 2];
    }

    // iteration 0 emits index 0 (scan emits `last` before update)
    float lx = base[0], ly = base[1], lz = base[2];
    if (t == 0) {
        float* o = new_xyz + (size_t)b * Sn * 3;
        o[0] = lx; o[1] = ly; o[2] = lz;
    }
    __syncthreads();  // stash visible

    for (int i = 1; i < Sn; ++i) {
        float best = -1.0f;
        int bp = 0;
        // FROZEN arithmetic: d = fma(dz,dz, fma(dx,dx, dy*dy)); strict >
        // coords from LDS: lane-consecutive addresses -> conflict-free
#define FPS_STEP(i) {                                              \
        int j##i = i * 512 + t;                                    \
        float dx = xs[j##i] - lx;                                  \
        float dy = ys[j##i] - ly;                                  \
        float dz = zs[j##i] - lz;                                  \
        float d = fmaf(dz, dz, fmaf(dx, dx, __fmul_rn(dy, dy)));   \
        float nd = fminf(dist##i, d);                              \
        dist##i = nd;                                              \
        bool u = nd > best;                                        \
        best = u ? nd : best;                                      \
        bp = u ? i : bp; }
        REP16(FPS_STEP)
#undef FPS_STEP

        // pack: high = f32 bits (non-negative => monotone), low = ~j so the
        // max key prefers the smallest original index on exact value ties
        u64 key = ((u64)__float_as_uint(best) << 32) |
                  (u64)(0xFFFFFFFFu - (u32)(bp * 512 + t));
#pragma unroll
        for (int off = 1; off < 64; off <<= 1) {
            u64 ok = __shfl_xor(key, off, 64);
            key = ok > key ? ok : key;
        }
        if (lane == 0) part[i & 1][wid] = key;
        __syncthreads();  // single barrier per iteration (double-buffered part)
        u64 k0 = part[i & 1][0], k1 = part[i & 1][1];
        u64 k2 = part[i & 1][2], k3 = part[i & 1][3];
        u64 k4 = part[i & 1][4], k5 = part[i & 1][5];
        u64 k6 = part[i & 1][6], k7 = part[i & 1][7];
        k0 = k0 > k1 ? k0 : k1;  k2 = k2 > k3 ? k2 : k3;
        k4 = k4 > k5 ? k4 : k5;  k6 = k6 > k7 ? k6 : k7;
        k0 = k0 > k2 ? k0 : k2;  k4 = k4 > k6 ? k4 : k6;
        u64 kw = k0 > k4 ? k0 : k4;
        u32 widx = 0xFFFFFFFFu - (u32)(kw & 0xFFFFFFFFull);
        // winner coords via LDS broadcast (uniform address across lanes)
        lx = xs[widx]; ly = ys[widx]; lz = zs[widx];
        if (t == 0) {
            float* o = new_xyz + ((size_t)b * Sn + i) * 3;
            o[0] = lx; o[1] = ly; o[2] = lz;
        }
    }
}

// ---------------------------------------------------------------------------
// Kernel 3: ball query — ARITHMETIC FROZEN (R23-verified):
//   d2 = fma(dz,dz, fma(dx,dx, dy*dy)),  strict d2 < f32(0.04)
// One wave per center; ballot-rank compaction, early exit once K found.
// ---------------------------------------------------------------------------
__global__ __launch_bounds__(256) void ballq_kernel(
    const float* __restrict__ xyz, const float* __restrict__ new_xyz,
    int* __restrict__ idx_int, float* __restrict__ out_idx)
{
    const int wlocal = threadIdx.x >> 6;
    const int lane = threadIdx.x & 63;
    const int gw = blockIdx.x * 4 + wlocal;   // center id, < 16384
    const int b = gw >> 11;                   // / 2048
    const float* base = xyz + (size_t)b * (Nn * 3);
    const float cx = new_xyz[(size_t)gw * 3 + 0];
    const float cy = new_xyz[(size_t)gw * 3 + 1];
    const float cz = new_xyz[(size_t)gw * 3 + 2];
    __shared__ int buf[4][Kn];
    const float R2 = 0.039999999105930328f;  // f32 nearest to 0.04
    int cnt = 0;
    for (int c = 0; c < Nn && cnt < Kn; c += 64) {
        int j = c + lane;
        float dx = base[j * 3 + 0] - cx;
        float dy = base[j * 3 + 1] - cy;
        float dz = base[j * 3 + 2] - cz;
        float d2 = fmaf(dz, dz, fmaf(dx, dx, __fmul_rn(dy, dy)));
        bool in = d2 < R2;  // strict
        u64 m = __ballot(in);
        int rank = (int)__popcll(m & ((1ull << lane) - 1ull));
        int pos = cnt + rank;
        if (in && pos < Kn) buf[wlocal][pos] = j;
        cnt += (int)__popcll(m);
    }
    __syncthreads();
    if (lane < Kn) {
        int first = buf[wlocal][0];  // center itself is in-ball => cnt >= 1
        int v = (lane < cnt) ? buf[wlocal][lane] : first;
        idx_int[(size_t)gw * Kn + lane] = v;
        out_idx[(size_t)gw * Kn + lane] = (float)v;
    }
}

// ---------------------------------------------------------------------------
// Kernel 4: fused grouped-MLP + maxpool (f32; tolerance is generous).
// ---------------------------------------------------------------------------
__global__ __launch_bounds__(128) void mlp_kernel(
    const float* __restrict__ xyz, const float* __restrict__ points,
    const float* __restrict__ new_xyz, const int* __restrict__ idx_int,
    const float* __restrict__ Wc, const float* __restrict__ bc,
    float* __restrict__ out_np)
{
    const int g = blockIdx.x;   // center id
    const int b = g >> 11;
    const int t = threadIdx.x;  // output channel
    float wcol[CIN];
#pragma unroll
    for (int c = 0; c < CIN; ++c) wcol[c] = Wc[c * COUT + t];
    const int* ip = idx_int + (size_t)g * Kn;
    const float* xb = xyz + (size_t)b * (Nn * 3);
    const float* pb = points + (size_t)b * (Nn * 32);
    float m = -3.4e38f;
    for (int k = 0; k < Kn; ++k) {
        int n = __builtin_amdgcn_readfirstlane(ip[k]);
        const float* xr = xb + n * 3;
        const float* pr = pb + (size_t)n * 32;
        float acc = xr[0] * wcol[0] + xr[1] * wcol[1] + xr[2] * wcol[2];
#pragma unroll
        for (int c = 0; c < 32; ++c) acc = fmaf(pr[c], wcol[3 + c], acc);
        m = fmaxf(m, acc);
    }
    const float cx = new_xyz[(size_t)g * 3 + 0];
    const float cy = new_xyz[(size_t)g * 3 + 1];
    const float cz = new_xyz[(size_t)g * 3 + 2];
    const float corr = cx * wcol[0] + cy * wcol[1] + cz * wcol[2];
    out_np[(size_t)g * COUT + t] = m - corr + bc[t];
}

// ---------------------------------------------------------------------------
extern "C" void kernel_launch(void* const* d_in, const int* in_sizes, int n_in,
                              void* d_out, int out_size, void* d_ws, size_t ws_size,
                              hipStream_t stream) {
    const float* xyz    = (const float*)d_in[0];
    const float* points = (const float*)d_in[1];
    const float* w0 = (const float*)d_in[2];
    const float* b0 = (const float*)d_in[3];
    const float* w1 = (const float*)d_in[4];
    const float* b1 = (const float*)d_in[5];
    const float* w2 = (const float*)d_in[6];
    const float* b2 = (const float*)d_in[7];

    float* out = (float*)d_out;
    float* o_newxyz = out;                         // [8,2048,3]   = 49152
    float* o_newpts = out + 49152;                 // [8,2048,128] = 2097152
    float* o_idx    = out + 49152 + 2097152;       // [8,2048,32]  = 524288 (as float)

    int*   idx_int = (int*)d_ws;                                   // 2 MiB
    float* Wc = (float*)((char*)d_ws + 2097152);                   // 17920 B
    float* bc = (float*)((char*)d_ws + 2097152 + 17920);           // 512 B

    const int fps_lds = 3 * Nn * 4;   // 96 KiB dynamic coord stash
    hipFuncSetAttribute(reinterpret_cast<const void*>(fps_kernel),
                        hipFuncAttributeMaxDynamicSharedMemorySize, fps_lds);

    fold_kernel<<<1, 128, 0, stream>>>(w0, b0, w1, b1, w2, b2, Wc, bc);
    fps_kernel<<<Bn, 512, fps_lds, stream>>>(xyz, o_newxyz);
    ballq_kernel<<<(Bn * Sn) / 4, 256, 0, stream>>>(xyz, o_newxyz, idx_int, o_idx);
    mlp_kernel<<<Bn * Sn, 128, 0, stream>>>(xyz, points, o_newxyz, idx_int, Wc, bc, o_newpts);
}

// Round 29
// 1654.394 us; speedup vs baseline: 1.5518x; 1.5518x over previous
//
#include <hip/hip_runtime.h>

typedef unsigned long long u64;
typedef unsigned int u32;

#define Bn 8
#define Nn 8192
#define Sn 2048
#define Kn 32
#define CIN 35
#define COUT 128

// ---------------------------------------------------------------------------
// Kernel 1: fold the 3 bias-only linear layers into one: Wc[35][128], bc[128]
// ---------------------------------------------------------------------------
__global__ __launch_bounds__(128) void fold_kernel(
    const float* __restrict__ w0, const float* __restrict__ b0,
    const float* __restrict__ w1, const float* __restrict__ b1,
    const float* __restrict__ w2, const float* __restrict__ b2,
    float* __restrict__ Wc, float* __restrict__ bc)
{
    __shared__ float W01[35][64];
    __shared__ float bb[64];
    const int t = threadIdx.x;
    for (int o = t; o < 35 * 64; o += 128) {
        int i = o >> 6, j = o & 63;
        float acc = 0.0f;
        for (int c = 0; c < 64; ++c) acc = fmaf(w0[i * 64 + c], w1[c * 64 + j], acc);
        W01[i][j] = acc;
    }
    for (int j = t; j < 64; j += 128) {
        float acc = b1[j];
        for (int c = 0; c < 64; ++c) acc = fmaf(b0[c], w1[c * 64 + j], acc);
        bb[j] = acc;
    }
    __syncthreads();
    for (int o = t; o < 35 * 128; o += 128) {
        int i = o >> 7, j = o & 127;
        float acc = 0.0f;
        for (int c = 0; c < 64; ++c) acc = fmaf(W01[i][c], w2[c * 128 + j], acc);
        Wc[o] = acc;
    }
    for (int j = t; j < 128; j += 128) {
        float acc = b2[j];
        for (int c = 0; c < 64; ++c) acc = fmaf(bb[c], w2[c * 128 + j], acc);
        bc[j] = acc;
    }
}

// ---------------------------------------------------------------------------
// Kernel 2: FPS — ARITHMETIC FROZEN (bit-exact vs mirror, R23-verified):
//   d = fma(dz,dz, fma(dx,dx, dy*dy)), f32 dist state, strict >, first-idx ties
// R29 perf change: the wave argmax reduce is now a DPP f32-max chain
// (6 VALU ops, zero LDS) + ballot/readlane tie-break, replacing the u64
// __shfl_xor butterfly (12 serialized ds_bpermute ~400-700cy — R26's tail).
// Tie-break preserved: leader = lowest candidate lane (lane order == index
// block order => smallest j); cross-wave u64 packed-key tree unchanged.
// Base structure = R26 (best known): 512 thr, 16 pts/thread in registers,
// 96KB LDS coord stash for the winner broadcast, 1 barrier/iter.
// ---------------------------------------------------------------------------
#define REP16(M) M(0) M(1) M(2) M(3) M(4) M(5) M(6) M(7) \
                 M(8) M(9) M(10) M(11) M(12) M(13) M(14) M(15)

__device__ __forceinline__ float wave_max_dpp(float v) {
    // canonical gfx9 wave64 max reduce; result in lane 63
#define DPPMAX(ctrl, rmask) {                                          \
        int mv = __builtin_amdgcn_update_dpp(                          \
            __float_as_int(v), __float_as_int(v), ctrl, rmask, 0xf, false); \
        v = fmaxf(v, __int_as_float(mv)); }
    DPPMAX(0x111, 0xf)   // row_shr:1
    DPPMAX(0x112, 0xf)   // row_shr:2
    DPPMAX(0x114, 0xf)   // row_shr:4
    DPPMAX(0x118, 0xf)   // row_shr:8
    DPPMAX(0x142, 0xa)   // row_bcast:15 -> rows 1,3
    DPPMAX(0x143, 0xc)   // row_bcast:31 -> rows 2,3
#undef DPPMAX
    return v;
}

__global__ __launch_bounds__(512, 1) void fps_kernel(
    const float* __restrict__ xyz, float* __restrict__ new_xyz)
{
    extern __shared__ float lds[];
    float* xs = lds;            // [8192]
    float* ys = lds + Nn;       // [8192]
    float* zs = lds + 2 * Nn;   // [8192]
    __shared__ u64 part[2][8];

    const int b = blockIdx.x;
    const int t = threadIdx.x;
    const int wid = t >> 6;  // 8 waves
    const int lane = t & 63;
    const float* base = xyz + (size_t)b * (Nn * 3);

#define FPS_DECL(i) float px##i, py##i, pz##i, dist##i;
    REP16(FPS_DECL)
#undef FPS_DECL

#define FPS_INIT(i) { int j = (t * 16 + i);                              \
        px##i = base[j * 3 + 0];                                         \
        py##i = base[j * 3 + 1];                                         \
        pz##i = base[j * 3 + 2];                                         \
        dist##i = 1e10f;                                                 \
        xs[j] = px##i; ys[j] = py##i; zs[j] = pz##i; }
    REP16(FPS_INIT)
#undef FPS_INIT

    // iteration 0 emits index 0 (scan emits `last` before update)
    float lx = base[0], ly = base[1], lz = base[2];
    if (t == 0) {
        float* o = new_xyz + (size_t)b * Sn * 3;
        o[0] = lx; o[1] = ly; o[2] = lz;
    }
    __syncthreads();  // stash visible

    for (int i = 1; i < Sn; ++i) {
        float best = -1.0f;
        int bp = 0;
        // FROZEN arithmetic: d = fma(dz,dz, fma(dx,dx, dy*dy)); strict >
#define FPS_STEP(i) {                                              \
        float dx = px##i - lx;                                     \
        float dy = py##i - ly;                                     \
        float dz = pz##i - lz;                                     \
        float d = fmaf(dz, dz, fmaf(dx, dx, __fmul_rn(dy, dy)));   \
        float nd = fminf(dist##i, d);                              \
        dist##i = nd;                                              \
        bool u = nd > best;                                        \
        best = u ? nd : best;                                      \
        bp = u ? i : bp; }
        REP16(FPS_STEP)
#undef FPS_STEP

        // wave argmax: DPP f32 max (VALU only) + ballot/readlane tie-break
        float wmax = wave_max_dpp(best);
        wmax = __int_as_float(__builtin_amdgcn_readlane(__float_as_int(wmax), 63));
        u64 cand = __ballot(best == wmax);
        int leader = (int)(__ffsll((long long)cand) - 1); // lowest lane => smallest j
        int bpl = __builtin_amdgcn_readlane(bp, leader);
        u32 jw = (u32)((wid * 64 + leader) * 16 + bpl);
        // pack: high = f32 bits (non-negative => monotone), low = ~j so the
        // max key prefers the smallest original index on exact value ties
        u64 key = ((u64)__float_as_uint(wmax) << 32) | (u64)(0xFFFFFFFFu - jw);
        if (lane == 0) part[i & 1][wid] = key;
        __syncthreads();  // single barrier per iteration (double-buffered part)
        u64 k0 = part[i & 1][0], k1 = part[i & 1][1];
        u64 k2 = part[i & 1][2], k3 = part[i & 1][3];
        u64 k4 = part[i & 1][4], k5 = part[i & 1][5];
        u64 k6 = part[i & 1][6], k7 = part[i & 1][7];
        k0 = k0 > k1 ? k0 : k1;  k2 = k2 > k3 ? k2 : k3;
        k4 = k4 > k5 ? k4 : k5;  k6 = k6 > k7 ? k6 : k7;
        k0 = k0 > k2 ? k0 : k2;  k4 = k4 > k6 ? k4 : k6;
        u64 kw = k0 > k4 ? k0 : k4;
        u32 widx = 0xFFFFFFFFu - (u32)(kw & 0xFFFFFFFFull);
        // winner coords via LDS broadcast (uniform address across lanes)
        lx = xs[widx]; ly = ys[widx]; lz = zs[widx];
        if (t == 0) {
            float* o = new_xyz + ((size_t)b * Sn + i) * 3;
            o[0] = lx; o[1] = ly; o[2] = lz;
        }
    }
}

// ---------------------------------------------------------------------------
// Kernel 3: ball query — ARITHMETIC FROZEN (R23-verified):
//   d2 = fma(dz,dz, fma(dx,dx, dy*dy)),  strict d2 < f32(0.04)
// One wave per center; ballot-rank compaction, early exit once K found.
// ---------------------------------------------------------------------------
__global__ __launch_bounds__(256) void ballq_kernel(
    const float* __restrict__ xyz, const float* __restrict__ new_xyz,
    int* __restrict__ idx_int, float* __restrict__ out_idx)
{
    const int wlocal = threadIdx.x >> 6;
    const int lane = threadIdx.x & 63;
    const int gw = blockIdx.x * 4 + wlocal;   // center id, < 16384
    const int b = gw >> 11;                   // / 2048
    const float* base = xyz + (size_t)b * (Nn * 3);
    const float cx = new_xyz[(size_t)gw * 3 + 0];
    const float cy = new_xyz[(size_t)gw * 3 + 1];
    const float cz = new_xyz[(size_t)gw * 3 + 2];
    __shared__ int buf[4][Kn];
    const float R2 = 0.039999999105930328f;  // f32 nearest to 0.04
    int cnt = 0;
    for (int c = 0; c < Nn && cnt < Kn; c += 64) {
        int j = c + lane;
        float dx = base[j * 3 + 0] - cx;
        float dy = base[j * 3 + 1] - cy;
        float dz = base[j * 3 + 2] - cz;
        float d2 = fmaf(dz, dz, fmaf(dx, dx, __fmul_rn(dy, dy)));
        bool in = d2 < R2;  // strict
        u64 m = __ballot(in);
        int rank = (int)__popcll(m & ((1ull << lane) - 1ull));
        int pos = cnt + rank;
        if (in && pos < Kn) buf[wlocal][pos] = j;
        cnt += (int)__popcll(m);
    }
    __syncthreads();
    if (lane < Kn) {
        int first = buf[wlocal][0];  // center itself is in-ball => cnt >= 1
        int v = (lane < cnt) ? buf[wlocal][lane] : first;
        idx_int[(size_t)gw * Kn + lane] = v;
        out_idx[(size_t)gw * Kn + lane] = (float)v;
    }
}

// ---------------------------------------------------------------------------
// Kernel 4: fused grouped-MLP + maxpool (f32; tolerance is generous).
// ---------------------------------------------------------------------------
__global__ __launch_bounds__(128) void mlp_kernel(
    const float* __restrict__ xyz, const float* __restrict__ points,
    const float* __restrict__ new_xyz, const int* __restrict__ idx_int,
    const float* __restrict__ Wc, const float* __restrict__ bc,
    float* __restrict__ out_np)
{
    const int g = blockIdx.x;   // center id
    const int b = g >> 11;
    const int t = threadIdx.x;  // output channel
    float wcol[CIN];
#pragma unroll
    for (int c = 0; c < CIN; ++c) wcol[c] = Wc[c * COUT + t];
    const int* ip = idx_int + (size_t)g * Kn;
    const float* xb = xyz + (size_t)b * (Nn * 3);
    const float* pb = points + (size_t)b * (Nn * 32);
    float m = -3.4e38f;
    for (int k = 0; k < Kn; ++k) {
        int n = __builtin_amdgcn_readfirstlane(ip[k]);
        const float* xr = xb + n * 3;
        const float* pr = pb + (size_t)n * 32;
        float acc = xr[0] * wcol[0] + xr[1] * wcol[1] + xr[2] * wcol[2];
#pragma unroll
        for (int c = 0; c < 32; ++c) acc = fmaf(pr[c], wcol[3 + c], acc);
        m = fmaxf(m, acc);
    }
    const float cx = new_xyz[(size_t)g * 3 + 0];
    const float cy = new_xyz[(size_t)g * 3 + 1];
    const float cz = new_xyz[(size_t)g * 3 + 2];
    const float corr = cx * wcol[0] + cy * wcol[1] + cz * wcol[2];
    out_np[(size_t)g * COUT + t] = m - corr + bc[t];
}

// ---------------------------------------------------------------------------
extern "C" void kernel_launch(void* const* d_in, const int* in_sizes, int n_in,
                              void* d_out, int out_size, void* d_ws, size_t ws_size,
                              hipStream_t stream) {
    const float* xyz    = (const float*)d_in[0];
    const float* points = (const float*)d_in[1];
    const float* w0 = (const float*)d_in[2];
    const float* b0 = (const float*)d_in[3];
    const float* w1 = (const float*)d_in[4];
    const float* b1 = (const float*)d_in[5];
    const float* w2 = (const float*)d_in[6];
    const float* b2 = (const float*)d_in[7];

    float* out = (float*)d_out;
    float* o_newxyz = out;                         // [8,2048,3]   = 49152
    float* o_newpts = out + 49152;                 // [8,2048,128] = 2097152
    float* o_idx    = out + 49152 + 2097152;       // [8,2048,32]  = 524288 (as float)

    int*   idx_int = (int*)d_ws;                                   // 2 MiB
    float* Wc = (float*)((char*)d_ws + 2097152);                   // 17920 B
    float* bc = (float*)((char*)d_ws + 2097152 + 17920);           // 512 B

    const int fps_lds = 3 * Nn * 4;   // 96 KiB dynamic coord stash
    hipFuncSetAttribute(reinterpret_cast<const void*>(fps_kernel),
                        hipFuncAttributeMaxDynamicSharedMemorySize, fps_lds);

    fold_kernel<<<1, 128, 0, stream>>>(w0, b0, w1, b1, w2, b2, Wc, bc);
    fps_kernel<<<Bn, 512, fps_lds, stream>>>(xyz, o_newxyz);
    ballq_kernel<<<(Bn * Sn) / 4, 256, 0, stream>>>(xyz, o_newxyz, idx_int, o_idx);
    mlp_kernel<<<Bn * Sn, 128, 0, stream>>>(xyz, points, o_newxyz, idx_int, Wc, bc, o_newpts);
}